// Round 1
// baseline (473.805 us; speedup 1.0000x reference)
//
#include <hip/hip_runtime.h>
#include <math.h>

// Problem constants (fixed by setup_inputs)
#define BS 4
#define NH 8
#define CH 64
#define TT 1024         // T = 32*32
#define WROWS 1536      // 3*NH*CH
#define NOBJ 8

// Workspace layout (floats)
#define FN_OFF   0
#define FF_OFF   6291456           // BS*WROWS*TT
#define AFG_OFF  12582912          // 2*BS*WROWS*TT
#define AFG_SZ   2097152           // BS*512*TT

__device__ __forceinline__ void get_region(const float* __restrict__ bb,
                                           int& i0, int& j0, int& hh, int& ww) {
    float x = bb[0], y = bb[1], bw = bb[2], bh = bb[3];
    float i0f = fminf(31.0f, floorf(y * 32.0f));
    float j0f = fminf(31.0f, floorf(x * 32.0f));
    float i1f = i0f + fmaxf(1.0f, ceilf(bh * 32.0f));
    float j1f = j0f + fmaxf(1.0f, ceilf(bw * 32.0f));
    i0 = (int)i0f; j0 = (int)j0f;
    int i1 = min(32, (int)i1f);
    int j1 = min(32, (int)j1f);
    hh = i1 - i0; ww = j1 - j0;
}

// ---------------------------------------------------------------------------
// Kernel 1: Fn = qkv + W @ null_emb ; Ff = qkv + W @ prompt_emb
// grid (16 t-tiles, 24 r-tiles, 4 b), block 256
// ---------------------------------------------------------------------------
__global__ __launch_bounds__(256)
void fuse_kernel(const float* __restrict__ qkv, const float* __restrict__ nEmb,
                 const float* __restrict__ pEmb, const float* __restrict__ W,
                 float* __restrict__ Fn, float* __restrict__ Ff) {
    __shared__ float WtT[64][68];   // [e][r] transposed W tile
    __shared__ float En[64][64];    // [e][t]
    __shared__ float Ep[64][64];
    int t0 = blockIdx.x * 64;
    int r0 = blockIdx.y * 64;
    int b  = blockIdx.z;
    int tid = threadIdx.x;
    int half = tid >> 4;            // 0..15
    int q4 = (tid & 15) * 4;
#pragma unroll
    for (int p = 0; p < 4; ++p) {
        int rr = p * 16 + half;
        float4 w4 = *(const float4*)&W[(r0 + rr) * 64 + q4];
        WtT[q4 + 0][rr] = w4.x; WtT[q4 + 1][rr] = w4.y;
        WtT[q4 + 2][rr] = w4.z; WtT[q4 + 3][rr] = w4.w;
        int e = p * 16 + half;
        *(float4*)&En[e][q4] = *(const float4*)&nEmb[(b * 64 + e) * TT + t0 + q4];
        *(float4*)&Ep[e][q4] = *(const float4*)&pEmb[(b * 64 + e) * TT + t0 + q4];
    }
    __syncthreads();
    int tr = tid >> 4, tc = tid & 15;
    float an[4][4] = {{0.f}}, ap[4][4] = {{0.f}};
#pragma unroll 8
    for (int e = 0; e < 64; ++e) {
        float4 w4 = *(const float4*)&WtT[e][tr * 4];
        float4 n4 = *(const float4*)&En[e][tc * 4];
        float4 p4 = *(const float4*)&Ep[e][tc * 4];
        float w[4]  = {w4.x, w4.y, w4.z, w4.w};
        float nn[4] = {n4.x, n4.y, n4.z, n4.w};
        float pp[4] = {p4.x, p4.y, p4.z, p4.w};
#pragma unroll
        for (int i = 0; i < 4; ++i)
#pragma unroll
            for (int j = 0; j < 4; ++j) {
                an[i][j] += w[i] * nn[j];
                ap[i][j] += w[i] * pp[j];
            }
    }
#pragma unroll
    for (int i = 0; i < 4; ++i) {
        int r = r0 + tr * 4 + i;
        int base = (b * WROWS + r) * TT + t0 + tc * 4;
        float4 x4 = *(const float4*)&qkv[base];
        float4 o1 = make_float4(x4.x + an[i][0], x4.y + an[i][1],
                                x4.z + an[i][2], x4.w + an[i][3]);
        float4 o2 = make_float4(x4.x + ap[i][0], x4.y + ap[i][1],
                                x4.z + ap[i][2], x4.w + ap[i][3]);
        *(float4*)&Fn[base] = o1;
        *(float4*)&Ff[base] = o2;
    }
}

// ---------------------------------------------------------------------------
// Kernel 2: null attention (flash style), writes a_null directly to out.
// grid (16 row-tiles, 32 bh), block 256. out layout: [b][h*64+c][t]
// ---------------------------------------------------------------------------
__global__ __launch_bounds__(256)
void attn_null_kernel(const float* __restrict__ Fn, float* __restrict__ out) {
    __shared__ float Qs[64][64];   // [c][t]  (scale^2 = 0.125 folded in)
    __shared__ float Ks[64][64];   // [c][s]
    __shared__ float Vt[64][68];   // [s][c]
    __shared__ float Pt[64][68];   // [s][t]
    int t0 = blockIdx.x * 64;
    int bh = blockIdx.y;
    int b = bh >> 3, h = bh & 7;
    int tid = threadIdx.x;
    int tr = tid >> 4, tc = tid & 15;
    int half = tid >> 4;
    int q4 = (tid & 15) * 4;
    int baseq = (b * WROWS + h * 192) * TT;
    int basek = baseq + 64 * TT;
    int basev = baseq + 128 * TT;
#pragma unroll
    for (int p = 0; p < 4; ++p) {
        int c = p * 16 + half;
        float4 v = *(const float4*)&Fn[baseq + c * TT + t0 + q4];
        v.x *= 0.125f; v.y *= 0.125f; v.z *= 0.125f; v.w *= 0.125f;
        *(float4*)&Qs[c][q4] = v;
    }
    float m[4], l[4], O[4][4];
#pragma unroll
    for (int i = 0; i < 4; ++i) {
        m[i] = -3.0e38f; l[i] = 0.f;
#pragma unroll
        for (int j = 0; j < 4; ++j) O[i][j] = 0.f;
    }
    for (int s0 = 0; s0 < TT; s0 += 64) {
#pragma unroll
        for (int p = 0; p < 4; ++p) {
            int c = p * 16 + half;
            *(float4*)&Ks[c][q4] = *(const float4*)&Fn[basek + c * TT + s0 + q4];
            float4 v = *(const float4*)&Fn[basev + c * TT + s0 + q4];
            Vt[q4 + 0][c] = v.x; Vt[q4 + 1][c] = v.y;
            Vt[q4 + 2][c] = v.z; Vt[q4 + 3][c] = v.w;
        }
        __syncthreads();
        float acc[4][4] = {{0.f}};
#pragma unroll 8
        for (int c = 0; c < 64; ++c) {
            float4 a4 = *(const float4*)&Qs[c][tr * 4];
            float4 b4 = *(const float4*)&Ks[c][tc * 4];
            float a[4] = {a4.x, a4.y, a4.z, a4.w};
            float bb[4] = {b4.x, b4.y, b4.z, b4.w};
#pragma unroll
            for (int i = 0; i < 4; ++i)
#pragma unroll
                for (int j = 0; j < 4; ++j) acc[i][j] += a[i] * bb[j];
        }
        float p_[4][4];
#pragma unroll
        for (int i = 0; i < 4; ++i) {
            float tm = fmaxf(fmaxf(acc[i][0], acc[i][1]), fmaxf(acc[i][2], acc[i][3]));
#pragma unroll
            for (int d = 1; d < 16; d <<= 1) tm = fmaxf(tm, __shfl_xor(tm, d, 64));
            float mn = fmaxf(m[i], tm);
            float alpha = __expf(m[i] - mn);
            m[i] = mn;
            float rs = 0.f;
#pragma unroll
            for (int j = 0; j < 4; ++j) { float e = __expf(acc[i][j] - mn); p_[i][j] = e; rs += e; }
#pragma unroll
            for (int d = 1; d < 16; d <<= 1) rs += __shfl_xor(rs, d, 64);
            l[i] = l[i] * alpha + rs;
#pragma unroll
            for (int j = 0; j < 4; ++j) O[i][j] *= alpha;
        }
#pragma unroll
        for (int j = 0; j < 4; ++j) {
            *(float4*)&Pt[tc * 4 + j][tr * 4] =
                make_float4(p_[0][j], p_[1][j], p_[2][j], p_[3][j]);
        }
        __syncthreads();
#pragma unroll 8
        for (int s = 0; s < 64; ++s) {
            float4 p4 = *(const float4*)&Pt[s][tr * 4];
            float4 v4 = *(const float4*)&Vt[s][tc * 4];
            float pp[4] = {p4.x, p4.y, p4.z, p4.w};
            float vv[4] = {v4.x, v4.y, v4.z, v4.w};
#pragma unroll
            for (int i = 0; i < 4; ++i)
#pragma unroll
                for (int j = 0; j < 4; ++j) O[i][j] += pp[i] * vv[j];
        }
        __syncthreads();
    }
    int obase = (b * 512 + h * 64) * TT;
#pragma unroll
    for (int i = 0; i < 4; ++i) { float inv = 1.0f / l[i];
#pragma unroll
        for (int j = 0; j < 4; ++j) O[i][j] *= inv; }
#pragma unroll
    for (int j = 0; j < 4; ++j) {
        *(float4*)&out[obase + (tc * 4 + j) * TT + t0 + tr * 4] =
            make_float4(O[0][j], O[1][j], O[2][j], O[3][j]);
    }
}

// ---------------------------------------------------------------------------
// Kernel 3: foreground attention per (row-tile, bh, object), region-restricted.
// Accumulates (softmaxed attn / 1) into afg with atomics; counter handled later.
// grid (16, 32, 8), block 256
// ---------------------------------------------------------------------------
__global__ __launch_bounds__(256)
void attn_fg_kernel(const float* __restrict__ Ff, const float* __restrict__ bboxes,
                    float* __restrict__ afg) {
    __shared__ float Qs[64][64];
    __shared__ float Ks[64][64];
    __shared__ float Vt[64][68];
    __shared__ float Pt[64][68];
    __shared__ int tmap[1024];
    int rt = blockIdx.x;
    int bh = blockIdx.y;
    int o  = blockIdx.z;
    int b = bh >> 3, h = bh & 7;
    int i0, j0, hh, ww;
    get_region(&bboxes[(b * NOBJ + o) * 5], i0, j0, hh, ww);
    int R = hh * ww;
    if (rt * 64 >= R) return;
    int tid = threadIdx.x;
    // region cell -> t map
    for (int idx = tid; idx < R; idx += 256) {
        int ri = idx / ww;
        int rj = idx - ri * ww;
        tmap[idx] = (i0 + ri) * 32 + j0 + rj;
    }
    __syncthreads();
    int tr = tid >> 4, tc = tid & 15;
    int baseq = (b * WROWS + h * 192) * TT;
    int basek = baseq + 64 * TT;
    int basev = baseq + 128 * TT;
    // stage Q rows for this row tile (clamped)
    for (int p = 0; p < 16; ++p) {
        int idx = p * 256 + tid;
        int c = idx >> 6, rl = idx & 63;
        int r = min(rt * 64 + rl, R - 1);
        Qs[c][rl] = Ff[baseq + c * TT + tmap[r]] * 0.125f;
    }
    float m[4], l[4], O[4][4];
#pragma unroll
    for (int i = 0; i < 4; ++i) {
        m[i] = -3.0e38f; l[i] = 0.f;
#pragma unroll
        for (int j = 0; j < 4; ++j) O[i][j] = 0.f;
    }
    int nct = (R + 63) >> 6;
    for (int ct = 0; ct < nct; ++ct) {
        int sb = ct * 64;
        for (int p = 0; p < 16; ++p) {
            int idx = p * 256 + tid;
            int c = idx >> 6, sl = idx & 63;
            int s = min(sb + sl, R - 1);
            int t = tmap[s];
            Ks[c][sl] = Ff[basek + c * TT + t];
            Vt[sl][c] = Ff[basev + c * TT + t];
        }
        __syncthreads();
        float acc[4][4] = {{0.f}};
#pragma unroll 8
        for (int c = 0; c < 64; ++c) {
            float4 a4 = *(const float4*)&Qs[c][tr * 4];
            float4 b4 = *(const float4*)&Ks[c][tc * 4];
            float a[4] = {a4.x, a4.y, a4.z, a4.w};
            float bb[4] = {b4.x, b4.y, b4.z, b4.w};
#pragma unroll
            for (int i = 0; i < 4; ++i)
#pragma unroll
                for (int j = 0; j < 4; ++j) acc[i][j] += a[i] * bb[j];
        }
        // mask invalid columns
#pragma unroll
        for (int j = 0; j < 4; ++j) {
            if (sb + tc * 4 + j >= R) {
#pragma unroll
                for (int i = 0; i < 4; ++i) acc[i][j] = -3.0e38f;
            }
        }
        float p_[4][4];
#pragma unroll
        for (int i = 0; i < 4; ++i) {
            float tm = fmaxf(fmaxf(acc[i][0], acc[i][1]), fmaxf(acc[i][2], acc[i][3]));
#pragma unroll
            for (int d = 1; d < 16; d <<= 1) tm = fmaxf(tm, __shfl_xor(tm, d, 64));
            float mn = fmaxf(m[i], tm);
            float alpha = __expf(m[i] - mn);
            m[i] = mn;
            float rs = 0.f;
#pragma unroll
            for (int j = 0; j < 4; ++j) { float e = __expf(acc[i][j] - mn); p_[i][j] = e; rs += e; }
#pragma unroll
            for (int d = 1; d < 16; d <<= 1) rs += __shfl_xor(rs, d, 64);
            l[i] = l[i] * alpha + rs;
#pragma unroll
            for (int j = 0; j < 4; ++j) O[i][j] *= alpha;
        }
#pragma unroll
        for (int j = 0; j < 4; ++j) {
            *(float4*)&Pt[tc * 4 + j][tr * 4] =
                make_float4(p_[0][j], p_[1][j], p_[2][j], p_[3][j]);
        }
        __syncthreads();
#pragma unroll 8
        for (int s = 0; s < 64; ++s) {
            float4 p4 = *(const float4*)&Pt[s][tr * 4];
            float4 v4 = *(const float4*)&Vt[s][tc * 4];
            float pp[4] = {p4.x, p4.y, p4.z, p4.w};
            float vv[4] = {v4.x, v4.y, v4.z, v4.w};
#pragma unroll
            for (int i = 0; i < 4; ++i)
#pragma unroll
                for (int j = 0; j < 4; ++j) O[i][j] += pp[i] * vv[j];
        }
        __syncthreads();
    }
    int obase = (b * 512 + h * 64) * TT;
#pragma unroll
    for (int i = 0; i < 4; ++i) {
        int r = rt * 64 + tr * 4 + i;
        if (r < R) {
            float inv = 1.0f / l[i];
            int t = tmap[r];
#pragma unroll
            for (int j = 0; j < 4; ++j) {
                unsafeAtomicAdd(&afg[obase + (tc * 4 + j) * TT + t], O[i][j] * inv);
            }
        }
    }
}

// ---------------------------------------------------------------------------
// Kernel 4: combine — counter recomputed from bboxes; out = afg/cnt where cnt>0
// grid 128, block 256 (one thread per (bh, t))
// ---------------------------------------------------------------------------
__global__ __launch_bounds__(256)
void combine_kernel(const float* __restrict__ bboxes, const float* __restrict__ afg,
                    float* __restrict__ out) {
    int gid = blockIdx.x * 256 + threadIdx.x;
    int bh = gid >> 10;
    int t = gid & 1023;
    int b = bh >> 3, h = bh & 7;
    int ti = t >> 5, tj = t & 31;
    int cnt = 0;
#pragma unroll
    for (int o = 0; o < NOBJ; ++o) {
        int i0, j0, hh, ww;
        get_region(&bboxes[(b * NOBJ + o) * 5], i0, j0, hh, ww);
        if (ti >= i0 && ti < i0 + hh && tj >= j0 && tj < j0 + ww) cnt++;
    }
    if (cnt == 0) return;
    float fc = (float)cnt;
    int base = (b * 512 + h * 64) * TT + t;
#pragma unroll 4
    for (int c = 0; c < 64; ++c) {
        out[base + c * TT] = afg[base + c * TT] / fc;
    }
}

extern "C" void kernel_launch(void* const* d_in, const int* in_sizes, int n_in,
                              void* d_out, int out_size, void* d_ws, size_t ws_size,
                              hipStream_t stream) {
    const float* qkv    = (const float*)d_in[0];
    const float* bboxes = (const float*)d_in[1];
    const float* nEmb   = (const float*)d_in[2];
    const float* pEmb   = (const float*)d_in[3];
    const float* W      = (const float*)d_in[4];
    float* ws  = (float*)d_ws;
    float* Fn  = ws + FN_OFF;
    float* Ff  = ws + FF_OFF;
    float* afg = ws + AFG_OFF;
    float* out = (float*)d_out;

    hipMemsetAsync(afg, 0, AFG_SZ * sizeof(float), stream);
    fuse_kernel<<<dim3(16, 24, 4), 256, 0, stream>>>(qkv, nEmb, pEmb, W, Fn, Ff);
    attn_null_kernel<<<dim3(16, 32), 256, 0, stream>>>(Fn, out);
    attn_fg_kernel<<<dim3(16, 32, 8), 256, 0, stream>>>(Ff, bboxes, afg);
    combine_kernel<<<128, 256, 0, stream>>>(bboxes, afg, out);
}

// Round 2
// 384.592 us; speedup vs baseline: 1.2320x; 1.2320x over previous
//
#include <hip/hip_runtime.h>
#include <math.h>

// Problem constants (fixed by setup_inputs)
#define BS 4
#define NH 8
#define CH 64
#define TT 1024         // T = 32*32
#define WROWS 1536      // 3*NH*CH
#define NOBJ 8

// Workspace layout (floats)
#define FN_OFF   0
#define FF_OFF   6291456           // BS*WROWS*TT
#define AFG_OFF  12582912          // 2*BS*WROWS*TT
#define AFG_SZ   2097152           // BS*512*TT

typedef __attribute__((ext_vector_type(8))) short short8;
typedef __attribute__((ext_vector_type(4))) float v4f;

__device__ __forceinline__ short f2bf(float f) {
    unsigned u = __float_as_uint(f);
    u = (u + 0x7FFF + ((u >> 16) & 1)) >> 16;   // RNE
    return (short)u;
}

__device__ __forceinline__ void get_region(const float* __restrict__ bb,
                                           int& i0, int& j0, int& hh, int& ww) {
    float x = bb[0], y = bb[1], bw = bb[2], bh = bb[3];
    float i0f = fminf(31.0f, floorf(y * 32.0f));
    float j0f = fminf(31.0f, floorf(x * 32.0f));
    float i1f = i0f + fmaxf(1.0f, ceilf(bh * 32.0f));
    float j1f = j0f + fmaxf(1.0f, ceilf(bw * 32.0f));
    i0 = (int)i0f; j0 = (int)j0f;
    int i1 = min(32, (int)i1f);
    int j1 = min(32, (int)j1f);
    hh = i1 - i0; ww = j1 - j0;
}

// ---------------------------------------------------------------------------
// Kernel 1: Fn = qkv + W @ null_emb ; Ff = qkv + W @ prompt_emb  (fp32 microtile)
// ---------------------------------------------------------------------------
__global__ __launch_bounds__(256)
void fuse_kernel(const float* __restrict__ qkv, const float* __restrict__ nEmb,
                 const float* __restrict__ pEmb, const float* __restrict__ W,
                 float* __restrict__ Fn, float* __restrict__ Ff) {
    __shared__ float WtT[64][68];
    __shared__ float En[64][64];
    __shared__ float Ep[64][64];
    int t0 = blockIdx.x * 64;
    int r0 = blockIdx.y * 64;
    int b  = blockIdx.z;
    int tid = threadIdx.x;
    int half = tid >> 4;
    int q4 = (tid & 15) * 4;
#pragma unroll
    for (int p = 0; p < 4; ++p) {
        int rr = p * 16 + half;
        float4 w4 = *(const float4*)&W[(r0 + rr) * 64 + q4];
        WtT[q4 + 0][rr] = w4.x; WtT[q4 + 1][rr] = w4.y;
        WtT[q4 + 2][rr] = w4.z; WtT[q4 + 3][rr] = w4.w;
        int e = p * 16 + half;
        *(float4*)&En[e][q4] = *(const float4*)&nEmb[(b * 64 + e) * TT + t0 + q4];
        *(float4*)&Ep[e][q4] = *(const float4*)&pEmb[(b * 64 + e) * TT + t0 + q4];
    }
    __syncthreads();
    int tr = tid >> 4, tc = tid & 15;
    float an[4][4] = {{0.f}}, ap[4][4] = {{0.f}};
#pragma unroll 8
    for (int e = 0; e < 64; ++e) {
        float4 w4 = *(const float4*)&WtT[e][tr * 4];
        float4 n4 = *(const float4*)&En[e][tc * 4];
        float4 p4 = *(const float4*)&Ep[e][tc * 4];
        float w[4]  = {w4.x, w4.y, w4.z, w4.w};
        float nn[4] = {n4.x, n4.y, n4.z, n4.w};
        float pp[4] = {p4.x, p4.y, p4.z, p4.w};
#pragma unroll
        for (int i = 0; i < 4; ++i)
#pragma unroll
            for (int j = 0; j < 4; ++j) {
                an[i][j] += w[i] * nn[j];
                ap[i][j] += w[i] * pp[j];
            }
    }
#pragma unroll
    for (int i = 0; i < 4; ++i) {
        int r = r0 + tr * 4 + i;
        int base = (b * WROWS + r) * TT + t0 + tc * 4;
        float4 x4 = *(const float4*)&qkv[base];
        float4 o1 = make_float4(x4.x + an[i][0], x4.y + an[i][1],
                                x4.z + an[i][2], x4.w + an[i][3]);
        float4 o2 = make_float4(x4.x + ap[i][0], x4.y + ap[i][1],
                                x4.z + ap[i][2], x4.w + ap[i][3]);
        *(float4*)&Fn[base] = o1;
        *(float4*)&Ff[base] = o2;
    }
}

// ---------------------------------------------------------------------------
// Kernel 2: null attention, bf16 MFMA flash. grid (16 t-tiles, 32 bh), 256 thr.
// LDS (shorts): Qs[64][72] @0, Ks[64][72] @4608, Vs[64][72] @9216 (c x s),
//               Ps[64][72] @13824 (4 waves x 16 rows). Epilogue Ot overlaps K/V.
// ---------------------------------------------------------------------------
__global__ __launch_bounds__(256)
void attn_null_mfma(const float* __restrict__ Fn, float* __restrict__ out) {
    __shared__ __align__(16) short lds[18432];
    short (*Qs)[72] = (short(*)[72])(lds);
    short (*Ks)[72] = (short(*)[72])(lds + 4608);
    short (*Vs)[72] = (short(*)[72])(lds + 9216);
    short (*Ps)[72] = (short(*)[72])(lds + 13824);
    int t0 = blockIdx.x * 64;
    int bh = blockIdx.y;
    int b = bh >> 3, h = bh & 7;
    int tid = threadIdx.x;
    int w = tid >> 6, lane = tid & 63, ln = lane & 15, qd = lane >> 4;
    int baseq = (b * WROWS + h * 192) * TT;
    int basek = baseq + 64 * TT;
    int basev = baseq + 128 * TT;
    // stage Q (scaled by 0.125 = scale^2)
#pragma unroll
    for (int p = 0; p < 4; ++p) {
        int c = p * 16 + (tid >> 4);
        int t4 = (tid & 15) * 4;
        float4 qv = *(const float4*)&Fn[baseq + c * TT + t0 + t4];
        Qs[t4 + 0][c] = f2bf(qv.x * 0.125f);
        Qs[t4 + 1][c] = f2bf(qv.y * 0.125f);
        Qs[t4 + 2][c] = f2bf(qv.z * 0.125f);
        Qs[t4 + 3][c] = f2bf(qv.w * 0.125f);
    }
    v4f O[4];
    float m[4], l[4];
#pragma unroll
    for (int r = 0; r < 4; ++r) { m[r] = -3.0e38f; l[r] = 0.f; }
#pragma unroll
    for (int cc = 0; cc < 4; ++cc) O[cc] = (v4f){0.f, 0.f, 0.f, 0.f};
    __syncthreads();
    short8 aq0 = *(const short8*)&Qs[16 * w + ln][qd * 8];
    short8 aq1 = *(const short8*)&Qs[16 * w + ln][32 + qd * 8];

    for (int s0 = 0; s0 < TT; s0 += 64) {
        __syncthreads();   // previous tile's K/V fully consumed
#pragma unroll
        for (int p = 0; p < 4; ++p) {
            int c = p * 16 + (tid >> 4);
            int s4 = (tid & 15) * 4;
            float4 kv = *(const float4*)&Fn[basek + c * TT + s0 + s4];
            Ks[s4 + 0][c] = f2bf(kv.x);
            Ks[s4 + 1][c] = f2bf(kv.y);
            Ks[s4 + 2][c] = f2bf(kv.z);
            Ks[s4 + 3][c] = f2bf(kv.w);
            float4 vv = *(const float4*)&Fn[basev + c * TT + s0 + s4];
            unsigned lo = (unsigned short)f2bf(vv.x) | ((unsigned)(unsigned short)f2bf(vv.y) << 16);
            unsigned hi = (unsigned short)f2bf(vv.z) | ((unsigned)(unsigned short)f2bf(vv.w) << 16);
            uint2 pk; pk.x = lo; pk.y = hi;
            *(uint2*)&Vs[c][s4] = pk;
        }
        __syncthreads();
        v4f S[4];
#pragma unroll
        for (int nn = 0; nn < 4; ++nn) {
            short8 b0 = *(const short8*)&Ks[nn * 16 + ln][qd * 8];
            short8 b1 = *(const short8*)&Ks[nn * 16 + ln][32 + qd * 8];
            v4f z = (v4f){0.f, 0.f, 0.f, 0.f};
            z = __builtin_amdgcn_mfma_f32_16x16x32_bf16(aq0, b0, z, 0, 0, 0);
            z = __builtin_amdgcn_mfma_f32_16x16x32_bf16(aq1, b1, z, 0, 0, 0);
            S[nn] = z;
        }
        // online softmax, rows = 4*qd + r
#pragma unroll
        for (int r = 0; r < 4; ++r) {
            float mt = fmaxf(fmaxf(S[0][r], S[1][r]), fmaxf(S[2][r], S[3][r]));
            mt = fmaxf(mt, __shfl_xor(mt, 1, 64));
            mt = fmaxf(mt, __shfl_xor(mt, 2, 64));
            mt = fmaxf(mt, __shfl_xor(mt, 4, 64));
            mt = fmaxf(mt, __shfl_xor(mt, 8, 64));
            float mn = fmaxf(m[r], mt);
            float al = __expf(m[r] - mn);
            m[r] = mn;
            float e0 = __expf(S[0][r] - mn);
            float e1 = __expf(S[1][r] - mn);
            float e2 = __expf(S[2][r] - mn);
            float e3 = __expf(S[3][r] - mn);
            float rs = e0 + e1 + e2 + e3;
            rs += __shfl_xor(rs, 1, 64);
            rs += __shfl_xor(rs, 2, 64);
            rs += __shfl_xor(rs, 4, 64);
            rs += __shfl_xor(rs, 8, 64);
            l[r] = l[r] * al + rs;
            O[0][r] *= al; O[1][r] *= al; O[2][r] *= al; O[3][r] *= al;
            int prow = w * 16 + 4 * qd + r;
            Ps[prow][ 0 + ln] = f2bf(e0);
            Ps[prow][16 + ln] = f2bf(e1);
            Ps[prow][32 + ln] = f2bf(e2);
            Ps[prow][48 + ln] = f2bf(e3);
        }
        // P (A-layout) and V (B-layout) MFMA
        short8 ap0 = *(const short8*)&Ps[w * 16 + ln][qd * 8];
        short8 ap1 = *(const short8*)&Ps[w * 16 + ln][32 + qd * 8];
#pragma unroll
        for (int cc = 0; cc < 4; ++cc) {
            short8 bv0 = *(const short8*)&Vs[cc * 16 + ln][qd * 8];
            short8 bv1 = *(const short8*)&Vs[cc * 16 + ln][32 + qd * 8];
            O[cc] = __builtin_amdgcn_mfma_f32_16x16x32_bf16(ap0, bv0, O[cc], 0, 0, 0);
            O[cc] = __builtin_amdgcn_mfma_f32_16x16x32_bf16(ap1, bv1, O[cc], 0, 0, 0);
        }
    }
    __syncthreads();
    // epilogue: transpose O to [c][t] in LDS (over dead K/V region), store float4
    float* Ot = (float*)(lds + 4608);   // [64][68]
#pragma unroll
    for (int r = 0; r < 4; ++r) {
        float inv = 1.0f / l[r];
        int tl = 16 * w + 4 * qd + r;
#pragma unroll
        for (int cc = 0; cc < 4; ++cc)
            Ot[(cc * 16 + ln) * 68 + tl] = O[cc][r] * inv;
    }
    __syncthreads();
    int obase = (b * 512 + h * 64) * TT;
#pragma unroll
    for (int p = 0; p < 4; ++p) {
        int c = p * 16 + (tid >> 4);
        int t4 = (tid & 15) * 4;
        *(float4*)&out[obase + c * TT + t0 + t4] = *(float4*)&Ot[c * 68 + t4];
    }
}

// ---------------------------------------------------------------------------
// Kernel 3: foreground attention, bf16 MFMA, region-compacted via tmap.
// grid (16 row-tiles, 32 bh, 8 obj), 256 thr. Atomic accumulate into afg.
// ---------------------------------------------------------------------------
__global__ __launch_bounds__(256)
void attn_fg_mfma(const float* __restrict__ Ff, const float* __restrict__ bboxes,
                  float* __restrict__ afg) {
    __shared__ __align__(16) short lds[18432];
    __shared__ int tmap[1024];
    short (*Qs)[72] = (short(*)[72])(lds);
    short (*Ks)[72] = (short(*)[72])(lds + 4608);
    short (*Vs)[72] = (short(*)[72])(lds + 9216);
    short (*Ps)[72] = (short(*)[72])(lds + 13824);
    int rt = blockIdx.x;
    int bh = blockIdx.y;
    int o  = blockIdx.z;
    int b = bh >> 3, h = bh & 7;
    int i0, j0, hh, ww;
    get_region(&bboxes[(b * NOBJ + o) * 5], i0, j0, hh, ww);
    int R = hh * ww;
    if (rt * 64 >= R) return;
    int tid = threadIdx.x;
    int w = tid >> 6, lane = tid & 63, ln = lane & 15, qd = lane >> 4;
    for (int idx = tid; idx < R; idx += 256) {
        int ri = idx / ww;
        int rj = idx - ri * ww;
        tmap[idx] = (i0 + ri) * 32 + j0 + rj;
    }
    __syncthreads();
    int baseq = (b * WROWS + h * 192) * TT;
    int basek = baseq + 64 * TT;
    int basev = baseq + 128 * TT;
    // stage Q rows of this row tile (clamped), lane = local row
    {
        int rq = min(rt * 64 + lane, R - 1);
        int tq = tmap[rq];
#pragma unroll
        for (int p = 0; p < 16; ++p) {
            int c = p * 4 + w;
            Qs[lane][c] = f2bf(0.125f * Ff[baseq + c * TT + tq]);
        }
    }
    v4f O[4];
    float m[4], l[4];
#pragma unroll
    for (int r = 0; r < 4; ++r) { m[r] = -3.0e38f; l[r] = 0.f; }
#pragma unroll
    for (int cc = 0; cc < 4; ++cc) O[cc] = (v4f){0.f, 0.f, 0.f, 0.f};
    __syncthreads();
    short8 aq0 = *(const short8*)&Qs[16 * w + ln][qd * 8];
    short8 aq1 = *(const short8*)&Qs[16 * w + ln][32 + qd * 8];

    int nct = (R + 63) >> 6;
    for (int ct = 0; ct < nct; ++ct) {
        int sb = ct * 64;
        __syncthreads();
        {
            int sg = min(sb + lane, R - 1);
            int ts = tmap[sg];
#pragma unroll
            for (int p = 0; p < 16; ++p) {
                int c = p * 4 + w;
                Ks[lane][c] = f2bf(Ff[basek + c * TT + ts]);
                Vs[c][lane] = f2bf(Ff[basev + c * TT + ts]);
            }
        }
        __syncthreads();
        v4f S[4];
#pragma unroll
        for (int nn = 0; nn < 4; ++nn) {
            short8 b0 = *(const short8*)&Ks[nn * 16 + ln][qd * 8];
            short8 b1 = *(const short8*)&Ks[nn * 16 + ln][32 + qd * 8];
            v4f z = (v4f){0.f, 0.f, 0.f, 0.f};
            z = __builtin_amdgcn_mfma_f32_16x16x32_bf16(aq0, b0, z, 0, 0, 0);
            z = __builtin_amdgcn_mfma_f32_16x16x32_bf16(aq1, b1, z, 0, 0, 0);
            S[nn] = z;
        }
        // mask invalid columns (col = sb + nn*16 + ln)
#pragma unroll
        for (int nn = 0; nn < 4; ++nn) {
            if (sb + nn * 16 + ln >= R)
                S[nn] = (v4f){-3.0e38f, -3.0e38f, -3.0e38f, -3.0e38f};
        }
#pragma unroll
        for (int r = 0; r < 4; ++r) {
            float mt = fmaxf(fmaxf(S[0][r], S[1][r]), fmaxf(S[2][r], S[3][r]));
            mt = fmaxf(mt, __shfl_xor(mt, 1, 64));
            mt = fmaxf(mt, __shfl_xor(mt, 2, 64));
            mt = fmaxf(mt, __shfl_xor(mt, 4, 64));
            mt = fmaxf(mt, __shfl_xor(mt, 8, 64));
            float mn = fmaxf(m[r], mt);
            float al = __expf(m[r] - mn);
            m[r] = mn;
            float e0 = __expf(S[0][r] - mn);
            float e1 = __expf(S[1][r] - mn);
            float e2 = __expf(S[2][r] - mn);
            float e3 = __expf(S[3][r] - mn);
            float rs = e0 + e1 + e2 + e3;
            rs += __shfl_xor(rs, 1, 64);
            rs += __shfl_xor(rs, 2, 64);
            rs += __shfl_xor(rs, 4, 64);
            rs += __shfl_xor(rs, 8, 64);
            l[r] = l[r] * al + rs;
            O[0][r] *= al; O[1][r] *= al; O[2][r] *= al; O[3][r] *= al;
            int prow = w * 16 + 4 * qd + r;
            Ps[prow][ 0 + ln] = f2bf(e0);
            Ps[prow][16 + ln] = f2bf(e1);
            Ps[prow][32 + ln] = f2bf(e2);
            Ps[prow][48 + ln] = f2bf(e3);
        }
        short8 ap0 = *(const short8*)&Ps[w * 16 + ln][qd * 8];
        short8 ap1 = *(const short8*)&Ps[w * 16 + ln][32 + qd * 8];
#pragma unroll
        for (int cc = 0; cc < 4; ++cc) {
            short8 bv0 = *(const short8*)&Vs[cc * 16 + ln][qd * 8];
            short8 bv1 = *(const short8*)&Vs[cc * 16 + ln][32 + qd * 8];
            O[cc] = __builtin_amdgcn_mfma_f32_16x16x32_bf16(ap0, bv0, O[cc], 0, 0, 0);
            O[cc] = __builtin_amdgcn_mfma_f32_16x16x32_bf16(ap1, bv1, O[cc], 0, 0, 0);
        }
    }
    int obase = (b * 512 + h * 64) * TT;
#pragma unroll
    for (int r = 0; r < 4; ++r) {
        int rg = rt * 64 + 16 * w + 4 * qd + r;
        if (rg < R) {
            float inv = 1.0f / l[r];
            int t = tmap[rg];
#pragma unroll
            for (int cc = 0; cc < 4; ++cc)
                unsafeAtomicAdd(&afg[obase + (cc * 16 + ln) * TT + t], O[cc][r] * inv);
        }
    }
}

// ---------------------------------------------------------------------------
// Kernel 4: combine — counter recomputed analytically from bboxes
// ---------------------------------------------------------------------------
__global__ __launch_bounds__(256)
void combine_kernel(const float* __restrict__ bboxes, const float* __restrict__ afg,
                    float* __restrict__ out) {
    int gid = blockIdx.x * 256 + threadIdx.x;
    int bh = gid >> 10;
    int t = gid & 1023;
    int b = bh >> 3, h = bh & 7;
    int ti = t >> 5, tj = t & 31;
    int cnt = 0;
#pragma unroll
    for (int o = 0; o < NOBJ; ++o) {
        int i0, j0, hh, ww;
        get_region(&bboxes[(b * NOBJ + o) * 5], i0, j0, hh, ww);
        if (ti >= i0 && ti < i0 + hh && tj >= j0 && tj < j0 + ww) cnt++;
    }
    if (cnt == 0) return;
    float fc = (float)cnt;
    int base = (b * 512 + h * 64) * TT + t;
#pragma unroll 4
    for (int c = 0; c < 64; ++c) {
        out[base + c * TT] = afg[base + c * TT] / fc;
    }
}

extern "C" void kernel_launch(void* const* d_in, const int* in_sizes, int n_in,
                              void* d_out, int out_size, void* d_ws, size_t ws_size,
                              hipStream_t stream) {
    const float* qkv    = (const float*)d_in[0];
    const float* bboxes = (const float*)d_in[1];
    const float* nEmb   = (const float*)d_in[2];
    const float* pEmb   = (const float*)d_in[3];
    const float* W      = (const float*)d_in[4];
    float* ws  = (float*)d_ws;
    float* Fn  = ws + FN_OFF;
    float* Ff  = ws + FF_OFF;
    float* afg = ws + AFG_OFF;
    float* out = (float*)d_out;

    hipMemsetAsync(afg, 0, AFG_SZ * sizeof(float), stream);
    fuse_kernel<<<dim3(16, 24, 4), 256, 0, stream>>>(qkv, nEmb, pEmb, W, Fn, Ff);
    attn_null_mfma<<<dim3(16, 32), 256, 0, stream>>>(Fn, out);
    attn_fg_mfma<<<dim3(16, 32, 8), 256, 0, stream>>>(Ff, bboxes, afg);
    combine_kernel<<<128, 256, 0, stream>>>(bboxes, afg, out);
}

// Round 3
// 254.634 us; speedup vs baseline: 1.8607x; 1.5104x over previous
//
#include <hip/hip_runtime.h>
#include <math.h>

// Problem constants (fixed by setup_inputs)
#define BS 4
#define NH 8
#define TT 1024         // T = 32*32
#define WROWS 1536      // 3*NH*CH
#define NOBJ 8
#define NT 65536        // per-bh tensor elems (64*1024)

// Workspace layout (short element offsets)
#define QNT_OFF  0
#define KNT_OFF  2097152
#define VNCS_OFF 4194304
#define QFT_OFF  6291456
#define KFT_OFF  8388608
#define VFT_OFF  10485760
#define AFG_BYTE_OFF 25165824
#define AFG_SZ   2097152        // floats

typedef __attribute__((ext_vector_type(8))) short short8;
typedef __attribute__((ext_vector_type(4))) float v4f;

__device__ __forceinline__ short f2bf(float f) {
    unsigned u = __float_as_uint(f);
    u = (u + 0x7FFF + ((u >> 16) & 1)) >> 16;   // RNE
    return (short)u;
}
__device__ __forceinline__ unsigned p2(float a, float b) {
    return (unsigned)(unsigned short)f2bf(a) | ((unsigned)(unsigned short)f2bf(b) << 16);
}

__device__ __forceinline__ void get_region(const float* __restrict__ bb,
                                           int& i0, int& j0, int& hh, int& ww) {
    float x = bb[0], y = bb[1], bw = bb[2], bh = bb[3];
    float i0f = fminf(31.0f, floorf(y * 32.0f));
    float j0f = fminf(31.0f, floorf(x * 32.0f));
    float i1f = i0f + fmaxf(1.0f, ceilf(bh * 32.0f));
    float j1f = j0f + fmaxf(1.0f, ceilf(bw * 32.0f));
    i0 = (int)i0f; j0 = (int)j0f;
    int i1 = min(32, (int)i1f);
    int j1 = min(32, (int)j1f);
    hh = i1 - i0; ww = j1 - j0;
}

// ---------------------------------------------------------------------------
// Kernel 1: fused projection + layout conversion to bf16.
// Each block = one 64-row section (exactly one of q/k/v of one head) x 64 t.
// q/k sections -> [bh][t][c] transposed bf16 (q scaled by 0.125);
// v section    -> null variant natural [bh][c][t], fg variant transposed.
// ---------------------------------------------------------------------------
__global__ __launch_bounds__(256)
void fuse_kernel(const float* __restrict__ qkv, const float* __restrict__ nEmb,
                 const float* __restrict__ pEmb, const float* __restrict__ W,
                 short* __restrict__ wsS) {
    __shared__ float WtT[64][68];
    __shared__ float En[64][64];
    __shared__ float Ep[64][64];
    short* sbuf = (short*)&WtT[0][0];   // 64x72 shorts = 9216 B, aliases WtT
    int t0 = blockIdx.x * 64;
    int r0 = blockIdx.y * 64;
    int b  = blockIdx.z;
    int tid = threadIdx.x;
    int half = tid >> 4;
    int q4 = (tid & 15) * 4;
#pragma unroll
    for (int p = 0; p < 4; ++p) {
        int rr = p * 16 + half;
        float4 w4 = *(const float4*)&W[(r0 + rr) * 64 + q4];
        WtT[q4 + 0][rr] = w4.x; WtT[q4 + 1][rr] = w4.y;
        WtT[q4 + 2][rr] = w4.z; WtT[q4 + 3][rr] = w4.w;
        int e = p * 16 + half;
        *(float4*)&En[e][q4] = *(const float4*)&nEmb[(b * 64 + e) * TT + t0 + q4];
        *(float4*)&Ep[e][q4] = *(const float4*)&pEmb[(b * 64 + e) * TT + t0 + q4];
    }
    __syncthreads();
    int tr = tid >> 4, tc = tid & 15;
    float an[4][4] = {{0.f}}, ap[4][4] = {{0.f}};
#pragma unroll 8
    for (int e = 0; e < 64; ++e) {
        float4 w4 = *(const float4*)&WtT[e][tr * 4];
        float4 n4 = *(const float4*)&En[e][tc * 4];
        float4 p4 = *(const float4*)&Ep[e][tc * 4];
        float w[4]  = {w4.x, w4.y, w4.z, w4.w};
        float nn[4] = {n4.x, n4.y, n4.z, n4.w};
        float pp[4] = {p4.x, p4.y, p4.z, p4.w};
#pragma unroll
        for (int i = 0; i < 4; ++i)
#pragma unroll
            for (int j = 0; j < 4; ++j) {
                an[i][j] += w[i] * nn[j];
                ap[i][j] += w[i] * pp[j];
            }
    }
    int sec = (r0 % 192) / 64;          // 0=q 1=k 2=v
    int h = r0 / 192, bh = b * 8 + h;
    float sc = (sec == 0) ? 0.125f : 1.0f;   // fold scale^2 into Q
#pragma unroll
    for (int i = 0; i < 4; ++i) {
        int r = r0 + tr * 4 + i;
        float4 x4 = *(const float4*)&qkv[(b * WROWS + r) * TT + t0 + tc * 4];
        an[i][0] = (an[i][0] + x4.x) * sc; an[i][1] = (an[i][1] + x4.y) * sc;
        an[i][2] = (an[i][2] + x4.z) * sc; an[i][3] = (an[i][3] + x4.w) * sc;
        ap[i][0] = (ap[i][0] + x4.x) * sc; ap[i][1] = (ap[i][1] + x4.y) * sc;
        ap[i][2] = (ap[i][2] + x4.z) * sc; ap[i][3] = (ap[i][3] + x4.w) * sc;
    }
    if (sec == 2) {
        // null V natural [c][t]
        short* Vn = wsS + VNCS_OFF + bh * NT;
#pragma unroll
        for (int i = 0; i < 4; ++i) {
            int c = tr * 4 + i;
            uint2 pk; pk.x = p2(an[i][0], an[i][1]); pk.y = p2(an[i][2], an[i][3]);
            *(uint2*)&Vn[c * TT + t0 + tc * 4] = pk;
        }
        // fg V transposed [t][c]
        short* dst = wsS + VFT_OFF + bh * NT + t0 * 64;
        __syncthreads();
#pragma unroll
        for (int i = 0; i < 4; ++i)
#pragma unroll
            for (int j = 0; j < 4; ++j)
                sbuf[(tc * 4 + j) * 72 + tr * 4 + i] = f2bf(ap[i][j]);
        __syncthreads();
#pragma unroll
        for (int rep = 0; rep < 2; ++rep) {
            int idx = rep * 256 + tid; int tl = idx >> 3, c8 = idx & 7;
            *(short8*)&dst[tl * 64 + c8 * 8] = *(const short8*)&sbuf[tl * 72 + c8 * 8];
        }
    } else {
        short* dn = wsS + (sec == 0 ? QNT_OFF : KNT_OFF) + bh * NT + t0 * 64;
        short* df = wsS + (sec == 0 ? QFT_OFF : KFT_OFF) + bh * NT + t0 * 64;
        __syncthreads();
#pragma unroll
        for (int i = 0; i < 4; ++i)
#pragma unroll
            for (int j = 0; j < 4; ++j)
                sbuf[(tc * 4 + j) * 72 + tr * 4 + i] = f2bf(an[i][j]);
        __syncthreads();
#pragma unroll
        for (int rep = 0; rep < 2; ++rep) {
            int idx = rep * 256 + tid; int tl = idx >> 3, c8 = idx & 7;
            *(short8*)&dn[tl * 64 + c8 * 8] = *(const short8*)&sbuf[tl * 72 + c8 * 8];
        }
        __syncthreads();
#pragma unroll
        for (int i = 0; i < 4; ++i)
#pragma unroll
            for (int j = 0; j < 4; ++j)
                sbuf[(tc * 4 + j) * 72 + tr * 4 + i] = f2bf(ap[i][j]);
        __syncthreads();
#pragma unroll
        for (int rep = 0; rep < 2; ++rep) {
            int idx = rep * 256 + tid; int tl = idx >> 3, c8 = idx & 7;
            *(short8*)&df[tl * 64 + c8 * 8] = *(const short8*)&sbuf[tl * 72 + c8 * 8];
        }
    }
}

// ---------------------------------------------------------------------------
// Kernel 2: null attention. grid (32 t-tiles of 32 rows, 32 bh), 128 threads
// (2 waves x 16 rows). Register-prefetch pipeline; P aliases dead Q.
// ---------------------------------------------------------------------------
__global__ __launch_bounds__(128)
void attn_null_mfma(const short* __restrict__ wsS, float* __restrict__ out) {
    __shared__ __align__(16) short lds[11520];
    short* Qs = lds;            // [32][72], later reused as Ps and Ot
    short* Ks = lds + 2304;     // [64][72]
    short* Vs = lds + 6912;     // [64][72]  ([c][s])
    int t0 = blockIdx.x * 32;
    int bh = blockIdx.y;
    int b = bh >> 3, h = bh & 7;
    const short* QnT = wsS + QNT_OFF + bh * NT;
    const short* KnT = wsS + KNT_OFF + bh * NT;
    const short* Vn  = wsS + VNCS_OFF + bh * NT;
    int tid = threadIdx.x;
    int w = tid >> 6, lane = tid & 63, ln = lane & 15, qd = lane >> 4;
#pragma unroll
    for (int rep = 0; rep < 2; ++rep) {
        int idx = rep * 128 + tid; int rl = idx >> 3, c8 = idx & 7;
        *(short8*)&Qs[rl * 72 + c8 * 8] = *(const short8*)&QnT[(t0 + rl) * 64 + c8 * 8];
    }
    __syncthreads();
    short8 aq0 = *(const short8*)&Qs[(16 * w + ln) * 72 + qd * 8];
    short8 aq1 = *(const short8*)&Qs[(16 * w + ln) * 72 + 32 + qd * 8];
    v4f O[4]; float m[4], l[4];
#pragma unroll
    for (int r = 0; r < 4; ++r) { m[r] = -3.0e38f; l[r] = 0.f; }
#pragma unroll
    for (int cc = 0; cc < 4; ++cc) O[cc] = (v4f){0.f, 0.f, 0.f, 0.f};

    short8 kreg[4], vreg[4];
    {
#pragma unroll
        for (int rep = 0; rep < 4; ++rep) {
            int idx = rep * 128 + tid; int a = idx >> 3, e8 = idx & 7;
            kreg[rep] = *(const short8*)&KnT[a * 64 + e8 * 8];
            vreg[rep] = *(const short8*)&Vn[a * TT + e8 * 8];
        }
    }
    for (int ct = 0; ct < 16; ++ct) {
        __syncthreads();
#pragma unroll
        for (int rep = 0; rep < 4; ++rep) {
            int idx = rep * 128 + tid; int a = idx >> 3, e8 = idx & 7;
            *(short8*)&Ks[a * 72 + e8 * 8] = kreg[rep];
            *(short8*)&Vs[a * 72 + e8 * 8] = vreg[rep];
        }
        __syncthreads();
        if (ct < 15) {
            int s0 = (ct + 1) * 64;
#pragma unroll
            for (int rep = 0; rep < 4; ++rep) {
                int idx = rep * 128 + tid; int a = idx >> 3, e8 = idx & 7;
                kreg[rep] = *(const short8*)&KnT[(s0 + a) * 64 + e8 * 8];
                vreg[rep] = *(const short8*)&Vn[a * TT + s0 + e8 * 8];
            }
        }
        v4f S[4];
#pragma unroll
        for (int nn = 0; nn < 4; ++nn) {
            short8 b0 = *(const short8*)&Ks[(nn * 16 + ln) * 72 + qd * 8];
            short8 b1 = *(const short8*)&Ks[(nn * 16 + ln) * 72 + 32 + qd * 8];
            v4f z = (v4f){0.f, 0.f, 0.f, 0.f};
            z = __builtin_amdgcn_mfma_f32_16x16x32_bf16(aq0, b0, z, 0, 0, 0);
            z = __builtin_amdgcn_mfma_f32_16x16x32_bf16(aq1, b1, z, 0, 0, 0);
            S[nn] = z;
        }
#pragma unroll
        for (int r = 0; r < 4; ++r) {
            float mt = fmaxf(fmaxf(S[0][r], S[1][r]), fmaxf(S[2][r], S[3][r]));
            mt = fmaxf(mt, __shfl_xor(mt, 1, 64));
            mt = fmaxf(mt, __shfl_xor(mt, 2, 64));
            mt = fmaxf(mt, __shfl_xor(mt, 4, 64));
            mt = fmaxf(mt, __shfl_xor(mt, 8, 64));
            float mn = fmaxf(m[r], mt);
            float al = __expf(m[r] - mn);
            m[r] = mn;
            float e0 = __expf(S[0][r] - mn);
            float e1 = __expf(S[1][r] - mn);
            float e2 = __expf(S[2][r] - mn);
            float e3 = __expf(S[3][r] - mn);
            float rs = e0 + e1 + e2 + e3;
            rs += __shfl_xor(rs, 1, 64);
            rs += __shfl_xor(rs, 2, 64);
            rs += __shfl_xor(rs, 4, 64);
            rs += __shfl_xor(rs, 8, 64);
            l[r] = l[r] * al + rs;
            O[0][r] *= al; O[1][r] *= al; O[2][r] *= al; O[3][r] *= al;
            int prow = (w * 16 + 4 * qd + r) * 72;
            Qs[prow +  0 + ln] = f2bf(e0);
            Qs[prow + 16 + ln] = f2bf(e1);
            Qs[prow + 32 + ln] = f2bf(e2);
            Qs[prow + 48 + ln] = f2bf(e3);
        }
        short8 ap0 = *(const short8*)&Qs[(w * 16 + ln) * 72 + qd * 8];
        short8 ap1 = *(const short8*)&Qs[(w * 16 + ln) * 72 + 32 + qd * 8];
#pragma unroll
        for (int cc = 0; cc < 4; ++cc) {
            short8 bv0 = *(const short8*)&Vs[(cc * 16 + ln) * 72 + qd * 8];
            short8 bv1 = *(const short8*)&Vs[(cc * 16 + ln) * 72 + 32 + qd * 8];
            O[cc] = __builtin_amdgcn_mfma_f32_16x16x32_bf16(ap0, bv0, O[cc], 0, 0, 0);
            O[cc] = __builtin_amdgcn_mfma_f32_16x16x32_bf16(ap1, bv1, O[cc], 0, 0, 0);
        }
    }
    __syncthreads();
    float* Ot = (float*)lds;   // [64][40] floats = 10240 B
#pragma unroll
    for (int r = 0; r < 4; ++r) {
        float inv = 1.0f / l[r];
        int tl = 16 * w + 4 * qd + r;
#pragma unroll
        for (int cc = 0; cc < 4; ++cc)
            Ot[(cc * 16 + ln) * 40 + tl] = O[cc][r] * inv;
    }
    __syncthreads();
    int obase = (b * 512 + h * 64) * TT + t0;
#pragma unroll
    for (int rep = 0; rep < 4; ++rep) {
        int idx = rep * 128 + tid; int c = idx >> 3, t4 = (idx & 7) * 4;
        *(float4*)&out[obase + c * TT + t4] = *(float4*)&Ot[c * 40 + t4];
    }
}

// ---------------------------------------------------------------------------
// Kernel 3: foreground attention, region-compacted, coalesced bf16 staging,
// register-prefetch pipeline. grid (16 rt, 32 bh, 8 obj), 256 threads.
// ---------------------------------------------------------------------------
__global__ __launch_bounds__(256)
void attn_fg_mfma(const short* __restrict__ wsS, const float* __restrict__ bboxes,
                  float* __restrict__ afg) {
    __shared__ __align__(16) short lds[13824];
    __shared__ unsigned short tmap[1024];
    short* Qs = lds;            // [64][72], aliased as Ps
    short* Ks = lds + 4608;     // [64][72]
    short* Vs = lds + 9216;     // [64][72]  ([c][s])
    int rt = blockIdx.x, bh = blockIdx.y, o = blockIdx.z;
    int b = bh >> 3, h = bh & 7;
    int i0, j0, hh, ww;
    get_region(&bboxes[(b * NOBJ + o) * 5], i0, j0, hh, ww);
    int R = hh * ww;
    if (rt * 64 >= R) return;
    int tid = threadIdx.x;
    int w = tid >> 6, lane = tid & 63, ln = lane & 15, qd = lane >> 4;
    const short* QfT = wsS + QFT_OFF + bh * NT;
    const short* KfT = wsS + KFT_OFF + bh * NT;
    const short* VfT = wsS + VFT_OFF + bh * NT;
    for (int idx = tid; idx < R; idx += 256) {
        int ri = idx / ww; int rj = idx - ri * ww;
        tmap[idx] = (unsigned short)((i0 + ri) * 32 + j0 + rj);
    }
    __syncthreads();
#pragma unroll
    for (int rep = 0; rep < 2; ++rep) {
        int idx = rep * 256 + tid; int cell = idx >> 3, c8 = idx & 7;
        int rq = min(rt * 64 + cell, R - 1);
        int t = tmap[rq];
        *(short8*)&Qs[cell * 72 + c8 * 8] = *(const short8*)&QfT[t * 64 + c8 * 8];
    }
    __syncthreads();
    short8 aq0 = *(const short8*)&Qs[(16 * w + ln) * 72 + qd * 8];
    short8 aq1 = *(const short8*)&Qs[(16 * w + ln) * 72 + 32 + qd * 8];
    v4f O[4]; float m[4], l[4];
#pragma unroll
    for (int r = 0; r < 4; ++r) { m[r] = -3.0e38f; l[r] = 0.f; }
#pragma unroll
    for (int cc = 0; cc < 4; ++cc) O[cc] = (v4f){0.f, 0.f, 0.f, 0.f};
    int nct = (R + 63) >> 6;
    short8 kreg[2], vreg[2];
    {
#pragma unroll
        for (int rep = 0; rep < 2; ++rep) {
            int idx = rep * 256 + tid; int cell = idx >> 3, c8 = idx & 7;
            int sg = min(cell, R - 1);
            int t = tmap[sg];
            kreg[rep] = *(const short8*)&KfT[t * 64 + c8 * 8];
            vreg[rep] = *(const short8*)&VfT[t * 64 + c8 * 8];
        }
    }
    for (int ct = 0; ct < nct; ++ct) {
        int sb = ct * 64;
        __syncthreads();
#pragma unroll
        for (int rep = 0; rep < 2; ++rep) {
            int idx = rep * 256 + tid; int cell = idx >> 3, c8 = idx & 7;
            *(short8*)&Ks[cell * 72 + c8 * 8] = kreg[rep];
#pragma unroll
            for (int j = 0; j < 8; ++j)          // V transpose scatter
                Vs[(c8 * 8 + j) * 72 + cell] = vreg[rep][j];
        }
        __syncthreads();
        if (ct + 1 < nct) {
            int s0 = sb + 64;
#pragma unroll
            for (int rep = 0; rep < 2; ++rep) {
                int idx = rep * 256 + tid; int cell = idx >> 3, c8 = idx & 7;
                int sg = min(s0 + cell, R - 1);
                int t = tmap[sg];
                kreg[rep] = *(const short8*)&KfT[t * 64 + c8 * 8];
                vreg[rep] = *(const short8*)&VfT[t * 64 + c8 * 8];
            }
        }
        v4f S[4];
#pragma unroll
        for (int nn = 0; nn < 4; ++nn) {
            short8 b0 = *(const short8*)&Ks[(nn * 16 + ln) * 72 + qd * 8];
            short8 b1 = *(const short8*)&Ks[(nn * 16 + ln) * 72 + 32 + qd * 8];
            v4f z = (v4f){0.f, 0.f, 0.f, 0.f};
            z = __builtin_amdgcn_mfma_f32_16x16x32_bf16(aq0, b0, z, 0, 0, 0);
            z = __builtin_amdgcn_mfma_f32_16x16x32_bf16(aq1, b1, z, 0, 0, 0);
            S[nn] = z;
        }
#pragma unroll
        for (int nn = 0; nn < 4; ++nn) {
            if (sb + nn * 16 + ln >= R)
                S[nn] = (v4f){-3.0e38f, -3.0e38f, -3.0e38f, -3.0e38f};
        }
#pragma unroll
        for (int r = 0; r < 4; ++r) {
            float mt = fmaxf(fmaxf(S[0][r], S[1][r]), fmaxf(S[2][r], S[3][r]));
            mt = fmaxf(mt, __shfl_xor(mt, 1, 64));
            mt = fmaxf(mt, __shfl_xor(mt, 2, 64));
            mt = fmaxf(mt, __shfl_xor(mt, 4, 64));
            mt = fmaxf(mt, __shfl_xor(mt, 8, 64));
            float mn = fmaxf(m[r], mt);
            float al = __expf(m[r] - mn);
            m[r] = mn;
            float e0 = __expf(S[0][r] - mn);
            float e1 = __expf(S[1][r] - mn);
            float e2 = __expf(S[2][r] - mn);
            float e3 = __expf(S[3][r] - mn);
            float rs = e0 + e1 + e2 + e3;
            rs += __shfl_xor(rs, 1, 64);
            rs += __shfl_xor(rs, 2, 64);
            rs += __shfl_xor(rs, 4, 64);
            rs += __shfl_xor(rs, 8, 64);
            l[r] = l[r] * al + rs;
            O[0][r] *= al; O[1][r] *= al; O[2][r] *= al; O[3][r] *= al;
            int prow = (w * 16 + 4 * qd + r) * 72;
            Qs[prow +  0 + ln] = f2bf(e0);
            Qs[prow + 16 + ln] = f2bf(e1);
            Qs[prow + 32 + ln] = f2bf(e2);
            Qs[prow + 48 + ln] = f2bf(e3);
        }
        short8 ap0 = *(const short8*)&Qs[(w * 16 + ln) * 72 + qd * 8];
        short8 ap1 = *(const short8*)&Qs[(w * 16 + ln) * 72 + 32 + qd * 8];
#pragma unroll
        for (int cc = 0; cc < 4; ++cc) {
            short8 bv0 = *(const short8*)&Vs[(cc * 16 + ln) * 72 + qd * 8];
            short8 bv1 = *(const short8*)&Vs[(cc * 16 + ln) * 72 + 32 + qd * 8];
            O[cc] = __builtin_amdgcn_mfma_f32_16x16x32_bf16(ap0, bv0, O[cc], 0, 0, 0);
            O[cc] = __builtin_amdgcn_mfma_f32_16x16x32_bf16(ap1, bv1, O[cc], 0, 0, 0);
        }
    }
    int obase = (b * 512 + h * 64) * TT;
#pragma unroll
    for (int r = 0; r < 4; ++r) {
        int rg = rt * 64 + 16 * w + 4 * qd + r;
        if (rg < R) {
            float inv = 1.0f / l[r];
            int t = tmap[rg];
#pragma unroll
            for (int cc = 0; cc < 4; ++cc)
                unsafeAtomicAdd(&afg[obase + (cc * 16 + ln) * TT + t], O[cc][r] * inv);
        }
    }
}

// ---------------------------------------------------------------------------
// Kernel 4: combine — counter recomputed analytically from bboxes
// ---------------------------------------------------------------------------
__global__ __launch_bounds__(256)
void combine_kernel(const float* __restrict__ bboxes, const float* __restrict__ afg,
                    float* __restrict__ out) {
    int gid = blockIdx.x * 256 + threadIdx.x;
    int bh = gid >> 10;
    int t = gid & 1023;
    int b = bh >> 3, h = bh & 7;
    int ti = t >> 5, tj = t & 31;
    int cnt = 0;
#pragma unroll
    for (int o = 0; o < NOBJ; ++o) {
        int i0, j0, hh, ww;
        get_region(&bboxes[(b * NOBJ + o) * 5], i0, j0, hh, ww);
        if (ti >= i0 && ti < i0 + hh && tj >= j0 && tj < j0 + ww) cnt++;
    }
    if (cnt == 0) return;
    float fc = (float)cnt;
    int base = (b * 512 + h * 64) * TT + t;
#pragma unroll 4
    for (int c = 0; c < 64; ++c) {
        out[base + c * TT] = afg[base + c * TT] / fc;
    }
}

extern "C" void kernel_launch(void* const* d_in, const int* in_sizes, int n_in,
                              void* d_out, int out_size, void* d_ws, size_t ws_size,
                              hipStream_t stream) {
    const float* qkv    = (const float*)d_in[0];
    const float* bboxes = (const float*)d_in[1];
    const float* nEmb   = (const float*)d_in[2];
    const float* pEmb   = (const float*)d_in[3];
    const float* W      = (const float*)d_in[4];
    short* wsS = (short*)d_ws;
    float* afg = (float*)((char*)d_ws + AFG_BYTE_OFF);
    float* out = (float*)d_out;

    hipMemsetAsync(afg, 0, AFG_SZ * sizeof(float), stream);
    fuse_kernel<<<dim3(16, 24, 4), 256, 0, stream>>>(qkv, nEmb, pEmb, W, wsS);
    attn_null_mfma<<<dim3(32, 32), 128, 0, stream>>>(wsS, out);
    attn_fg_mfma<<<dim3(16, 32, 8), 256, 0, stream>>>(wsS, bboxes, afg);
    combine_kernel<<<128, 256, 0, stream>>>(bboxes, afg, out);
}

// Round 5
// 160.462 us; speedup vs baseline: 2.9527x; 1.5869x over previous
//
#include <hip/hip_runtime.h>
#include <math.h>

// Problem constants (fixed by setup_inputs)
#define BS 4
#define NH 8
#define TT 1024         // T = 32*32
#define WROWS 1536      // 3*NH*CH
#define NOBJ 8
#define NT 65536        // per-bh tensor elems (64*1024)

// Workspace layout (short element offsets)
#define QNT_OFF  0
#define KNT_OFF  2097152
#define VNCS_OFF 4194304
#define QFT_OFF  6291456
#define KFT_OFF  8388608
#define VFT_OFF  10485760

typedef __attribute__((ext_vector_type(8))) short short8;
typedef __attribute__((ext_vector_type(4))) float v4f;

__device__ __forceinline__ short f2bf(float f) {
    unsigned u = __float_as_uint(f);
    u = (u + 0x7FFF + ((u >> 16) & 1)) >> 16;   // RNE
    return (short)u;
}
__device__ __forceinline__ unsigned p2(float a, float b) {
    return (unsigned)(unsigned short)f2bf(a) | ((unsigned)(unsigned short)f2bf(b) << 16);
}

__device__ __forceinline__ void get_region(const float* __restrict__ bb,
                                           int& i0, int& j0, int& hh, int& ww) {
    float x = bb[0], y = bb[1], bw = bb[2], bh = bb[3];
    float i0f = fminf(31.0f, floorf(y * 32.0f));
    float j0f = fminf(31.0f, floorf(x * 32.0f));
    float i1f = i0f + fmaxf(1.0f, ceilf(bh * 32.0f));
    float j1f = j0f + fmaxf(1.0f, ceilf(bw * 32.0f));
    i0 = (int)i0f; j0 = (int)j0f;
    int i1 = min(32, (int)i1f);
    int j1 = min(32, (int)j1f);
    hh = i1 - i0; ww = j1 - j0;
}

// ---------------------------------------------------------------------------
// Kernel 1: fused projection + layout conversion to bf16.
// q/k sections -> [bh][t][c] transposed bf16 (q scaled by 0.125);
// v section    -> null variant natural [bh][c][t], fg variant transposed.
// ---------------------------------------------------------------------------
__global__ __launch_bounds__(256)
void fuse_kernel(const float* __restrict__ qkv, const float* __restrict__ nEmb,
                 const float* __restrict__ pEmb, const float* __restrict__ W,
                 short* __restrict__ wsS) {
    __shared__ float WtT[64][68];
    __shared__ float En[64][64];
    __shared__ float Ep[64][64];
    short* sbuf = (short*)&WtT[0][0];   // 64x72 shorts = 9216 B, aliases WtT
    int t0 = blockIdx.x * 64;
    int r0 = blockIdx.y * 64;
    int b  = blockIdx.z;
    int tid = threadIdx.x;
    int half = tid >> 4;
    int q4 = (tid & 15) * 4;
#pragma unroll
    for (int p = 0; p < 4; ++p) {
        int rr = p * 16 + half;
        float4 w4 = *(const float4*)&W[(r0 + rr) * 64 + q4];
        WtT[q4 + 0][rr] = w4.x; WtT[q4 + 1][rr] = w4.y;
        WtT[q4 + 2][rr] = w4.z; WtT[q4 + 3][rr] = w4.w;
        int e = p * 16 + half;
        *(float4*)&En[e][q4] = *(const float4*)&nEmb[(b * 64 + e) * TT + t0 + q4];
        *(float4*)&Ep[e][q4] = *(const float4*)&pEmb[(b * 64 + e) * TT + t0 + q4];
    }
    __syncthreads();
    int tr = tid >> 4, tc = tid & 15;
    float an[4][4] = {{0.f}}, ap[4][4] = {{0.f}};
#pragma unroll 8
    for (int e = 0; e < 64; ++e) {
        float4 w4 = *(const float4*)&WtT[e][tr * 4];
        float4 n4 = *(const float4*)&En[e][tc * 4];
        float4 p4 = *(const float4*)&Ep[e][tc * 4];
        float w[4]  = {w4.x, w4.y, w4.z, w4.w};
        float nn[4] = {n4.x, n4.y, n4.z, n4.w};
        float pp[4] = {p4.x, p4.y, p4.z, p4.w};
#pragma unroll
        for (int i = 0; i < 4; ++i)
#pragma unroll
            for (int j = 0; j < 4; ++j) {
                an[i][j] += w[i] * nn[j];
                ap[i][j] += w[i] * pp[j];
            }
    }
    int sec = (r0 % 192) / 64;          // 0=q 1=k 2=v
    int h = r0 / 192, bh = b * 8 + h;
    float sc = (sec == 0) ? 0.125f : 1.0f;   // fold scale^2 into Q
#pragma unroll
    for (int i = 0; i < 4; ++i) {
        int r = r0 + tr * 4 + i;
        float4 x4 = *(const float4*)&qkv[(b * WROWS + r) * TT + t0 + tc * 4];
        an[i][0] = (an[i][0] + x4.x) * sc; an[i][1] = (an[i][1] + x4.y) * sc;
        an[i][2] = (an[i][2] + x4.z) * sc; an[i][3] = (an[i][3] + x4.w) * sc;
        ap[i][0] = (ap[i][0] + x4.x) * sc; ap[i][1] = (ap[i][1] + x4.y) * sc;
        ap[i][2] = (ap[i][2] + x4.z) * sc; ap[i][3] = (ap[i][3] + x4.w) * sc;
    }
    if (sec == 2) {
        // null V natural [c][t]
        short* Vn = wsS + VNCS_OFF + bh * NT;
#pragma unroll
        for (int i = 0; i < 4; ++i) {
            int c = tr * 4 + i;
            uint2 pk; pk.x = p2(an[i][0], an[i][1]); pk.y = p2(an[i][2], an[i][3]);
            *(uint2*)&Vn[c * TT + t0 + tc * 4] = pk;
        }
        // fg V transposed [t][c]
        short* dst = wsS + VFT_OFF + bh * NT + t0 * 64;
        __syncthreads();
#pragma unroll
        for (int i = 0; i < 4; ++i)
#pragma unroll
            for (int j = 0; j < 4; ++j)
                sbuf[(tc * 4 + j) * 72 + tr * 4 + i] = f2bf(ap[i][j]);
        __syncthreads();
#pragma unroll
        for (int rep = 0; rep < 2; ++rep) {
            int idx = rep * 256 + tid; int tl = idx >> 3, c8 = idx & 7;
            *(short8*)&dst[tl * 64 + c8 * 8] = *(const short8*)&sbuf[tl * 72 + c8 * 8];
        }
    } else {
        short* dn = wsS + (sec == 0 ? QNT_OFF : KNT_OFF) + bh * NT + t0 * 64;
        short* df = wsS + (sec == 0 ? QFT_OFF : KFT_OFF) + bh * NT + t0 * 64;
        __syncthreads();
#pragma unroll
        for (int i = 0; i < 4; ++i)
#pragma unroll
            for (int j = 0; j < 4; ++j)
                sbuf[(tc * 4 + j) * 72 + tr * 4 + i] = f2bf(an[i][j]);
        __syncthreads();
#pragma unroll
        for (int rep = 0; rep < 2; ++rep) {
            int idx = rep * 256 + tid; int tl = idx >> 3, c8 = idx & 7;
            *(short8*)&dn[tl * 64 + c8 * 8] = *(const short8*)&sbuf[tl * 72 + c8 * 8];
        }
        __syncthreads();
#pragma unroll
        for (int i = 0; i < 4; ++i)
#pragma unroll
            for (int j = 0; j < 4; ++j)
                sbuf[(tc * 4 + j) * 72 + tr * 4 + i] = f2bf(ap[i][j]);
        __syncthreads();
#pragma unroll
        for (int rep = 0; rep < 2; ++rep) {
            int idx = rep * 256 + tid; int tl = idx >> 3, c8 = idx & 7;
            *(short8*)&df[tl * 64 + c8 * 8] = *(const short8*)&sbuf[tl * 72 + c8 * 8];
        }
    }
}

// ---------------------------------------------------------------------------
// Kernel 2: FUSED null + foreground attention. grid (16 row-tiles, 32 bh),
// 256 threads. Per block: null flash over its 64 natural-t rows, then per
// intersecting object a region-restricted flash; register accumulation of
// Oacc/cnt; single write of out. No atomics. Fixed softmax shift (m=0).
// ---------------------------------------------------------------------------
__global__ __launch_bounds__(256)
void attn_fused(const short* __restrict__ wsS, const float* __restrict__ bboxes,
                float* __restrict__ out) {
    __shared__ __align__(16) short lds[13824];
    __shared__ unsigned short tmap[1024];
    short* Qs = lds;            // [64][72], aliased as Ps (wave-private rows)
    short* Ks = lds + 4608;     // [64][72]  ([s][c])
    short* Vs = lds + 9216;     // [64][72]  ([c][s])
    int rt = blockIdx.x, bh = blockIdx.y;
    int b = bh >> 3, h = bh & 7;
    int t0 = rt * 64;
    int tid = threadIdx.x;
    int w = tid >> 6, lane = tid & 63, ln = lane & 15, qd = lane >> 4;
    const short* QnT = wsS + QNT_OFF + bh * NT;
    const short* KnT = wsS + KNT_OFF + bh * NT;
    const short* Vn  = wsS + VNCS_OFF + bh * NT;
    const short* QfT = wsS + QFT_OFF + bh * NT;
    const short* KfT = wsS + KFT_OFF + bh * NT;
    const short* VfT = wsS + VFT_OFF + bh * NT;
    int sidx = tid, scell = sidx >> 3, sc8 = sidx & 7;      // staging coords lo
    int sidx2 = 256 + tid, scell2 = sidx2 >> 3, sc82 = sidx2 & 7;

    // ================= Phase 1: null attention =================
    *(short8*)&Qs[scell * 72 + sc8 * 8]  = *(const short8*)&QnT[(t0 + scell) * 64 + sc8 * 8];
    *(short8*)&Qs[scell2 * 72 + sc82 * 8] = *(const short8*)&QnT[(t0 + scell2) * 64 + sc82 * 8];
    __syncthreads();
    short8 aq0 = *(const short8*)&Qs[(16 * w + ln) * 72 + qd * 8];
    short8 aq1 = *(const short8*)&Qs[(16 * w + ln) * 72 + 32 + qd * 8];
    v4f O[4]; float l[4];
#pragma unroll
    for (int r = 0; r < 4; ++r) l[r] = 0.f;
#pragma unroll
    for (int cc = 0; cc < 4; ++cc) O[cc] = (v4f){0.f, 0.f, 0.f, 0.f};
    short8 kreg[2], vreg[2];
    kreg[0] = *(const short8*)&KnT[scell * 64 + sc8 * 8];
    kreg[1] = *(const short8*)&KnT[scell2 * 64 + sc82 * 8];
    vreg[0] = *(const short8*)&Vn[scell * TT + sc8 * 8];
    vreg[1] = *(const short8*)&Vn[scell2 * TT + sc82 * 8];
    for (int ct = 0; ct < 16; ++ct) {
        __syncthreads();
        *(short8*)&Ks[scell * 72 + sc8 * 8]  = kreg[0];
        *(short8*)&Ks[scell2 * 72 + sc82 * 8] = kreg[1];
        *(short8*)&Vs[scell * 72 + sc8 * 8]  = vreg[0];     // Vn already [c][t]
        *(short8*)&Vs[scell2 * 72 + sc82 * 8] = vreg[1];
        __syncthreads();
        if (ct < 15) {
            int s0 = (ct + 1) * 64;
            kreg[0] = *(const short8*)&KnT[(s0 + scell) * 64 + sc8 * 8];
            kreg[1] = *(const short8*)&KnT[(s0 + scell2) * 64 + sc82 * 8];
            vreg[0] = *(const short8*)&Vn[scell * TT + s0 + sc8 * 8];
            vreg[1] = *(const short8*)&Vn[scell2 * TT + s0 + sc82 * 8];
        }
        v4f S[4];
#pragma unroll
        for (int nn = 0; nn < 4; ++nn) {
            short8 b0 = *(const short8*)&Ks[(nn * 16 + ln) * 72 + qd * 8];
            short8 b1 = *(const short8*)&Ks[(nn * 16 + ln) * 72 + 32 + qd * 8];
            v4f z = (v4f){0.f, 0.f, 0.f, 0.f};
            z = __builtin_amdgcn_mfma_f32_16x16x32_bf16(aq0, b0, z, 0, 0, 0);
            z = __builtin_amdgcn_mfma_f32_16x16x32_bf16(aq1, b1, z, 0, 0, 0);
            S[nn] = z;
        }
#pragma unroll
        for (int r = 0; r < 4; ++r) {
            float e0 = __expf(S[0][r]);
            float e1 = __expf(S[1][r]);
            float e2 = __expf(S[2][r]);
            float e3 = __expf(S[3][r]);
            l[r] += e0 + e1 + e2 + e3;
            int prow = (w * 16 + 4 * qd + r) * 72;
            Qs[prow +  0 + ln] = f2bf(e0);
            Qs[prow + 16 + ln] = f2bf(e1);
            Qs[prow + 32 + ln] = f2bf(e2);
            Qs[prow + 48 + ln] = f2bf(e3);
        }
        short8 ap0 = *(const short8*)&Qs[(w * 16 + ln) * 72 + qd * 8];
        short8 ap1 = *(const short8*)&Qs[(w * 16 + ln) * 72 + 32 + qd * 8];
#pragma unroll
        for (int cc = 0; cc < 4; ++cc) {
            short8 bv0 = *(const short8*)&Vs[(cc * 16 + ln) * 72 + qd * 8];
            short8 bv1 = *(const short8*)&Vs[(cc * 16 + ln) * 72 + 32 + qd * 8];
            O[cc] = __builtin_amdgcn_mfma_f32_16x16x32_bf16(ap0, bv0, O[cc], 0, 0, 0);
            O[cc] = __builtin_amdgcn_mfma_f32_16x16x32_bf16(ap1, bv1, O[cc], 0, 0, 0);
        }
    }
    v4f Onull[4];
#pragma unroll
    for (int r = 0; r < 4; ++r) {
        float rs = l[r];
        rs += __shfl_xor(rs, 1, 64);
        rs += __shfl_xor(rs, 2, 64);
        rs += __shfl_xor(rs, 4, 64);
        rs += __shfl_xor(rs, 8, 64);
        float inv = 1.0f / rs;
#pragma unroll
        for (int cc = 0; cc < 4; ++cc) Onull[cc][r] = O[cc][r] * inv;
    }

    // ================= Phase 2: foreground objects =================
    __syncthreads();
    *(short8*)&Qs[scell * 72 + sc8 * 8]  = *(const short8*)&QfT[(t0 + scell) * 64 + sc8 * 8];
    *(short8*)&Qs[scell2 * 72 + sc82 * 8] = *(const short8*)&QfT[(t0 + scell2) * 64 + sc82 * 8];
    __syncthreads();
    aq0 = *(const short8*)&Qs[(16 * w + ln) * 72 + qd * 8];
    aq1 = *(const short8*)&Qs[(16 * w + ln) * 72 + 32 + qd * 8];
    v4f Oacc[4]; float cnt[4];
#pragma unroll
    for (int r = 0; r < 4; ++r) cnt[r] = 0.f;
#pragma unroll
    for (int cc = 0; cc < 4; ++cc) Oacc[cc] = (v4f){0.f, 0.f, 0.f, 0.f};

    for (int o = 0; o < NOBJ; ++o) {
        int i0, j0, hh, ww;
        get_region(&bboxes[(b * NOBJ + o) * 5], i0, j0, hh, ww);
        int i1 = i0 + hh;
        if (i0 > 2 * rt + 1 || i1 <= 2 * rt) continue;   // uniform per block
        int R = hh * ww;
        for (int idx = tid; idx < R; idx += 256) {
            int ri = idx / ww; int rj = idx - ri * ww;
            tmap[idx] = (unsigned short)((i0 + ri) * 32 + j0 + rj);
        }
        __syncthreads();
#pragma unroll
        for (int r = 0; r < 4; ++r) l[r] = 0.f;
#pragma unroll
        for (int cc = 0; cc < 4; ++cc) O[cc] = (v4f){0.f, 0.f, 0.f, 0.f};
        int nct = (R + 63) >> 6;
        {
            int tA = tmap[min(scell, R - 1)];
            int tB = tmap[min(scell2, R - 1)];
            kreg[0] = *(const short8*)&KfT[tA * 64 + sc8 * 8];
            kreg[1] = *(const short8*)&KfT[tB * 64 + sc82 * 8];
            vreg[0] = *(const short8*)&VfT[tA * 64 + sc8 * 8];
            vreg[1] = *(const short8*)&VfT[tB * 64 + sc82 * 8];
        }
        for (int ct = 0; ct < nct; ++ct) {
            int sb = ct * 64;
            __syncthreads();
            *(short8*)&Ks[scell * 72 + sc8 * 8]  = kreg[0];
            *(short8*)&Ks[scell2 * 72 + sc82 * 8] = kreg[1];
            // rotated transpose scatter into Vs [c][s] (bank-conflict-free)
#pragma unroll
            for (int jj = 0; jj < 8; ++jj) {
                int j = (jj + sc8) & 7;
                Vs[(sc8 * 8 + j) * 72 + scell] = vreg[0][j];
            }
#pragma unroll
            for (int jj = 0; jj < 8; ++jj) {
                int j = (jj + sc82) & 7;
                Vs[(sc82 * 8 + j) * 72 + scell2] = vreg[1][j];
            }
            __syncthreads();
            if (ct + 1 < nct) {
                int s0 = sb + 64;
                int tA = tmap[min(s0 + scell, R - 1)];
                int tB = tmap[min(s0 + scell2, R - 1)];
                kreg[0] = *(const short8*)&KfT[tA * 64 + sc8 * 8];
                kreg[1] = *(const short8*)&KfT[tB * 64 + sc82 * 8];
                vreg[0] = *(const short8*)&VfT[tA * 64 + sc8 * 8];
                vreg[1] = *(const short8*)&VfT[tB * 64 + sc82 * 8];
            }
            v4f S[4];
#pragma unroll
            for (int nn = 0; nn < 4; ++nn) {
                short8 b0 = *(const short8*)&Ks[(nn * 16 + ln) * 72 + qd * 8];
                short8 b1 = *(const short8*)&Ks[(nn * 16 + ln) * 72 + 32 + qd * 8];
                v4f z = (v4f){0.f, 0.f, 0.f, 0.f};
                z = __builtin_amdgcn_mfma_f32_16x16x32_bf16(aq0, b0, z, 0, 0, 0);
                z = __builtin_amdgcn_mfma_f32_16x16x32_bf16(aq1, b1, z, 0, 0, 0);
                S[nn] = z;
            }
            float v0 = (sb +  0 + ln) < R ? 1.f : 0.f;
            float v1 = (sb + 16 + ln) < R ? 1.f : 0.f;
            float v2 = (sb + 32 + ln) < R ? 1.f : 0.f;
            float v3 = (sb + 48 + ln) < R ? 1.f : 0.f;
#pragma unroll
            for (int r = 0; r < 4; ++r) {
                float e0 = __expf(S[0][r]) * v0;
                float e1 = __expf(S[1][r]) * v1;
                float e2 = __expf(S[2][r]) * v2;
                float e3 = __expf(S[3][r]) * v3;
                l[r] += e0 + e1 + e2 + e3;
                int prow = (w * 16 + 4 * qd + r) * 72;
                Qs[prow +  0 + ln] = f2bf(e0);
                Qs[prow + 16 + ln] = f2bf(e1);
                Qs[prow + 32 + ln] = f2bf(e2);
                Qs[prow + 48 + ln] = f2bf(e3);
            }
            short8 ap0 = *(const short8*)&Qs[(w * 16 + ln) * 72 + qd * 8];
            short8 ap1 = *(const short8*)&Qs[(w * 16 + ln) * 72 + 32 + qd * 8];
#pragma unroll
            for (int cc = 0; cc < 4; ++cc) {
                short8 bv0 = *(const short8*)&Vs[(cc * 16 + ln) * 72 + qd * 8];
                short8 bv1 = *(const short8*)&Vs[(cc * 16 + ln) * 72 + 32 + qd * 8];
                O[cc] = __builtin_amdgcn_mfma_f32_16x16x32_bf16(ap0, bv0, O[cc], 0, 0, 0);
                O[cc] = __builtin_amdgcn_mfma_f32_16x16x32_bf16(ap1, bv1, O[cc], 0, 0, 0);
            }
        }
        // finalize object: accumulate rows inside region
#pragma unroll
        for (int r = 0; r < 4; ++r) {
            float rs = l[r];
            rs += __shfl_xor(rs, 1, 64);
            rs += __shfl_xor(rs, 2, 64);
            rs += __shfl_xor(rs, 4, 64);
            rs += __shfl_xor(rs, 8, 64);
            float inv = 1.0f / rs;
            int t = t0 + 16 * w + 4 * qd + r;
            int ti = t >> 5, tj = t & 31;
            bool in = (ti >= i0) && (ti < i1) && (tj >= j0) && (tj < j0 + ww);
            if (in) {
                cnt[r] += 1.f;
#pragma unroll
                for (int cc = 0; cc < 4; ++cc) Oacc[cc][r] += O[cc][r] * inv;
            }
        }
    }

    // ================= Epilogue =================
    __syncthreads();
    float* Ot = (float*)lds;   // [64][68] floats = 17408 B (fits in 27648 B)
#pragma unroll
    for (int r = 0; r < 4; ++r) {
        int tl = 16 * w + 4 * qd + r;
        float icnt = cnt[r] > 0.f ? 1.0f / cnt[r] : 0.f;
#pragma unroll
        for (int cc = 0; cc < 4; ++cc) {
            float val = cnt[r] > 0.f ? Oacc[cc][r] * icnt : Onull[cc][r];
            Ot[(cc * 16 + ln) * 68 + tl] = val;
        }
    }
    __syncthreads();
    int obase = (b * 512 + h * 64) * TT + t0;
#pragma unroll
    for (int rep = 0; rep < 4; ++rep) {
        int idx = rep * 256 + tid; int c = idx >> 4, t4 = (idx & 15) * 4;
        *(float4*)&out[obase + c * TT + t4] = *(float4*)&Ot[c * 68 + t4];
    }
}

extern "C" void kernel_launch(void* const* d_in, const int* in_sizes, int n_in,
                              void* d_out, int out_size, void* d_ws, size_t ws_size,
                              hipStream_t stream) {
    const float* qkv    = (const float*)d_in[0];
    const float* bboxes = (const float*)d_in[1];
    const float* nEmb   = (const float*)d_in[2];
    const float* pEmb   = (const float*)d_in[3];
    const float* W      = (const float*)d_in[4];
    short* wsS = (short*)d_ws;
    float* out = (float*)d_out;

    fuse_kernel<<<dim3(16, 24, 4), 256, 0, stream>>>(qkv, nEmb, pEmb, W, wsS);
    attn_fused<<<dim3(16, 32), 256, 0, stream>>>(wsS, bboxes, out);
}